// Round 16
// baseline (100.548 us; speedup 1.0000x reference)
//
#include <hip/hip_runtime.h>
#include <math.h>

#define NIN 64
#define CAP 16
#define GSEG 250
#define POOL_SPLIT 8
#define BND 128            // nodes per bucket
#define BSH 7              // log2(BND)
#define CHUNK 1024         // edges per hist/scatter chunk
#define NBMAX 1024         // max buckets / chunks for scans
#define OVR 128            // per-bucket overflow region (global)

__device__ __forceinline__ float wave_reduce_sum(float v) {
    #pragma unroll
    for (int off = 32; off > 0; off >>= 1) v += __shfl_xor(v, off);
    return v;
}

__device__ __forceinline__ unsigned short f2bf(float f) {
    unsigned int u = __float_as_uint(f);
    u += 0x7FFFu + ((u >> 16) & 1u);   // round-to-nearest-even
    return (unsigned short)(u >> 16);
}
__device__ __forceinline__ float bf2f(unsigned short h) {
    return __uint_as_float(((unsigned int)h) << 16);
}
__device__ __forceinline__ float bflo(unsigned int u) { return __uint_as_float(u << 16); }
__device__ __forceinline__ float bfhi(unsigned int u) { return __uint_as_float(u & 0xFFFF0000u); }
__device__ __forceinline__ unsigned int pack2bf(float lo, float hi) {
    return (unsigned int)f2bf(lo) | ((unsigned int)f2bf(hi) << 16);
}

// 15-bit float for w in (0,1]: 5-bit exp, 10-bit mantissa.
__device__ __forceinline__ unsigned int f15enc(float w) {
    unsigned int u = __float_as_uint(w);           // w >= 0
    u += 0x0FFFu + ((u >> 13) & 1u);               // RNE to 10-bit mantissa
    int e5 = (int)(u >> 23) - 96;
    if (e5 <= 0) return 0u;                        // underflow -> 0 (negligible)
    unsigned int m = (u >> 13) & 0x3FFu;
    if (e5 > 31) { e5 = 31; m = 0x3FFu; }
    return ((unsigned int)e5 << 10) | m;
}
__device__ __forceinline__ float f15dec(unsigned int f) {
    if (f == 0u) return 0.0f;
    return __uint_as_float((((f >> 10) + 96u) << 23) | ((f & 0x3FFu) << 13));
}

// exclusive prefix of x across the 64-lane wave
__device__ __forceinline__ int wave_excl_scan_int(int x, int lane) {
    int inc = x;
    #pragma unroll
    for (int off = 1; off < 64; off <<= 1) {
        int y = __shfl_up(inc, off);
        if (lane >= off) inc += y;
    }
    return inc - x;
}

// wave0: exclusive scan of src[0..nb) (nb <= 1024) into dst (LDS).
__device__ __forceinline__ void scan_btot(const int* __restrict__ src,
                                          int* dst, int nb, int tid) {
    if (tid < 64) {
        int v[16];
        #pragma unroll
        for (int j = 0; j < 16; ++j) {
            int idx = tid * 16 + j;
            v[j] = (idx < nb) ? src[idx] : 0;
        }
        int loc = 0;
        #pragma unroll
        for (int j = 0; j < 16; ++j) loc += v[j];
        int ex = wave_excl_scan_int(loc, tid);
        int run = ex;
        #pragma unroll
        for (int j = 0; j < 16; ++j) {
            int idx = tid * 16 + j;
            if (idx < nb) { dst[idx] = run; run += v[j]; }
        }
    }
}

// prep: x16 = bf16(x); zero out/bounds; per-chunk LDS histogram.
__global__ void __launch_bounds__(256)
k_prep(ushort4* __restrict__ x164, const float4* __restrict__ x4,
       float* __restrict__ out, int* __restrict__ gstart, int* __restrict__ gend,
       const int* __restrict__ col, int* __restrict__ ghist,
       int n, int e, int nb, int nblk) {
    __shared__ int h[NBMAX];
    int tid = threadIdx.x, blk = blockIdx.x;
    int i = blk * 256 + tid;
    int tot = n * (NIN / 4);
    if (i < tot) {
        float4 v = x4[i];
        ushort4 hh;
        hh.x = f2bf(v.x); hh.y = f2bf(v.y); hh.z = f2bf(v.z); hh.w = f2bf(v.w);
        x164[i] = hh;
    }
    if (i < GSEG * NIN) out[i] = 0.0f;
    if (i < GSEG) { gstart[i] = 0; gend[i] = 0; }
    if (blk < nblk) {
        for (int j = tid; j < NBMAX; j += 256) h[j] = 0;
        __syncthreads();
        int base = blk * CHUNK;
        int end = base + CHUNK; if (end > e) end = e;
        for (int j = base + tid; j < end; j += 256) atomicAdd(&h[col[j] >> BSH], 1);
        __syncthreads();
        for (int b = tid; b < nb; b += 256) ghist[blk * nb + b] = h[b];
    }
}

// scanA: per-bucket exclusive scan across chunks (wave0, 16/lane -> 1024 chunks);
// segment bounds via grid stride.
__global__ void __launch_bounds__(256)
k_scanA(int* __restrict__ ghist, int* __restrict__ btot,
        const int* __restrict__ seg, int* __restrict__ gstart,
        int* __restrict__ gend, int nblk, int nb, int n) {
    int tid = threadIdx.x;
    int b = blockIdx.x;   // grid = nb
    if (tid < 64) {
        int lane = tid;
        int v[16];
        #pragma unroll
        for (int j = 0; j < 16; ++j) {
            int idx = lane * 16 + j;
            v[j] = (idx < nblk) ? ghist[idx * nb + b] : 0;
        }
        int loc = 0;
        #pragma unroll
        for (int j = 0; j < 16; ++j) loc += v[j];
        int ex = wave_excl_scan_int(loc, lane);
        int run = ex;
        #pragma unroll
        for (int j = 0; j < 16; ++j) {
            int idx = lane * 16 + j;
            if (idx < nblk) { int t = v[j]; ghist[idx * nb + b] = run; run += t; }
        }
        if (lane == 63) btot[b] = ex + loc;
    }
    int gsz = gridDim.x * 256;
    for (int i = b * 256 + tid; i < n; i += gsz) {
        int s = seg[i];
        if (i == 0 || seg[i - 1] != s) gstart[s] = i;
        if (i == n - 1 || seg[i + 1] != s) gend[s] = i + 1;
    }
}

// scatter: records (r, cl|f15(ew)) sorted by bucket in LDS, contiguous copy-out.
__global__ void __launch_bounds__(256)
k_scatter(const int* __restrict__ row, const int* __restrict__ col,
          const float* __restrict__ ew, const int* __restrict__ ghist,
          const int* __restrict__ btot, uint2* __restrict__ bins,
          int e, int nb) {
    __shared__ int h[NBMAX];
    __shared__ int loff[NBMAX];
    __shared__ int gdst[NBMAX];
    __shared__ int bb[NBMAX];
    __shared__ uint2 recs[CHUNK];
    __shared__ unsigned short rb[CHUNK];
    int tid = threadIdx.x, blk = blockIdx.x;
    int base = blk * CHUNK;
    int end = base + CHUNK; if (end > e) end = e;
    int cntc = end - base;

    for (int i = tid; i < NBMAX; i += 256) h[i] = 0;
    __syncthreads();
    for (int i = base + tid; i < end; i += 256) atomicAdd(&h[col[i] >> BSH], 1);
    __syncthreads();
    if (tid < 64) {
        int v[16];
        #pragma unroll
        for (int j = 0; j < 16; ++j) {
            int idx = tid * 16 + j;
            v[j] = (idx < nb) ? h[idx] : 0;
        }
        int loc = 0;
        #pragma unroll
        for (int j = 0; j < 16; ++j) loc += v[j];
        int ex = wave_excl_scan_int(loc, tid);
        int run = ex;
        #pragma unroll
        for (int j = 0; j < 16; ++j) {
            int idx = tid * 16 + j;
            if (idx < nb) { loff[idx] = run; run += v[j]; }
        }
    }
    scan_btot(btot, bb, nb, tid);
    __syncthreads();
    for (int b = tid; b < nb; b += 256) gdst[b] = bb[b] + ghist[blk * nb + b];
    for (int i = tid; i < NBMAX; i += 256) h[i] = 0;
    __syncthreads();
    for (int i = base + tid; i < end; i += 256) {
        int c = col[i], r = row[i];
        int b = c >> BSH;
        uint2 rec;
        rec.x = (unsigned int)r;
        rec.y = ((unsigned int)(c & (BND - 1)) << 15) | f15enc(ew[i]);
        int k = atomicAdd(&h[b], 1);
        int idx = loff[b] + k;
        recs[idx] = rec;
        rb[idx] = (unsigned short)b;
    }
    __syncthreads();
    for (int i = tid; i < cntc; i += 256) {
        int b = rb[i];
        bins[(size_t)gdst[b] + (i - loff[b])] = recs[i];
    }
}

// deg2: one block per bucket, degree in LDS from contiguous records, dinv out.
__global__ void __launch_bounds__(256)
k_deg2(const uint2* __restrict__ bins, const int* __restrict__ btot,
       float* __restrict__ dinv, int n, int nb) {
    __shared__ float sdeg[BND];
    __shared__ int bb[NBMAX];
    int tid = threadIdx.x;
    int b = blockIdx.x;
    int c0 = b << BSH;
    if (tid < BND) sdeg[tid] = 0.0f;
    scan_btot(btot, bb, nb, tid);
    __syncthreads();
    int s0 = bb[b], tot = btot[b];
    for (int i = tid; i < tot; i += 256) {
        uint2 rec = bins[(size_t)s0 + i];
        int cl = (int)((rec.y >> 15) & (BND - 1));
        atomicAdd(&sdeg[cl], f15dec(rec.y & 0x7FFFu));
    }
    __syncthreads();
    if (tid < BND && c0 + tid < n) dinv[c0 + tid] = rsqrtf(sdeg[tid] + 1.0f);
}

// build: bake FULL weight into int2 (r, w_f32) ELL; overflow to per-bucket
// global region (consumed inline by gather). No aggf, no zeroing pass.
__global__ void __launch_bounds__(256)
k_build(const uint2* __restrict__ bins, const int* __restrict__ btot,
        const float* __restrict__ dinv, int2* __restrict__ ell2,
        int* __restrict__ cnt, int* __restrict__ ovfc, int2* __restrict__ ovfe,
        int n, int nb) {
    __shared__ int2 tile[BND * CAP];   // 16 KB
    __shared__ float sdv[BND];
    __shared__ int scnt[BND];
    __shared__ int bb[NBMAX];
    __shared__ int2 sovf[OVR];
    __shared__ int sovn;
    int tid = threadIdx.x;
    int b = blockIdx.x;
    int c0 = b << BSH;

    if (tid < BND) {
        scnt[tid] = 0;
        int c = c0 + tid;
        sdv[tid] = dinv[c < n ? c : (n - 1)];
    }
    if (tid == 0) sovn = 0;
    scan_btot(btot, bb, nb, tid);
    __syncthreads();

    int s0 = bb[b], tot = btot[b];
    for (int i = tid; i < tot; i += 256) {
        uint2 rec = bins[(size_t)s0 + i];
        int cl = (int)((rec.y >> 15) & (BND - 1));
        int r = (int)rec.x;
        float w = f15dec(rec.y & 0x7FFFu) * dinv[r] * sdv[cl];
        int slot = atomicAdd(&scnt[cl], 1);
        if (slot < CAP) {
            tile[cl * CAP + slot] = make_int2(r, __float_as_int(w));
        } else {
            int oi = atomicAdd(&sovn, 1);
            if (oi < OVR) sovf[oi] = make_int2((r << BSH) | cl, __float_as_int(w));
        }
    }
    __syncthreads();
    int nn = n - c0; if (nn > BND) nn = BND;
    for (int i = tid; i < nn * CAP; i += 256)
        ell2[(size_t)c0 * CAP + i] = tile[i];
    if (tid < nn) cnt[c0 + tid] = scnt[tid];
    int nov = sovn < OVR ? sovn : OVR;
    if (tid == 0) ovfc[b] = nov;
    for (int i = tid; i < nov; i += 256) ovfe[(size_t)b * OVR + i] = sovf[i];
}

// gather: 3125 blocks x 32 nodes. 8 nodes/wave, 8 lanes/node. Pure int2 ELL
// (exact FULLY-baked weights incl. dinv[c]): inner loop = shfl + row load +
// 8 FMA. NOTE: no trailing di multiply — weights are complete.
__global__ void __launch_bounds__(256)
k_gather(const ushort* __restrict__ x16, const float* __restrict__ dinv,
         const int* __restrict__ cnt, const int2* __restrict__ ell2,
         const int* __restrict__ ovfc, const int2* __restrict__ ovfe,
         ushort* __restrict__ agg16, const float* __restrict__ Wp,
         const float* __restrict__ bp, float* __restrict__ score, int n) {
    int tid = threadIdx.x, blk = blockIdx.x;
    int lane = tid & 63, wv = tid >> 6;
    int o = lane >> 3, l = lane & 7;
    int c = blk * 32 + wv * 8 + o;
    bool valid = c < n;
    int cc = valid ? c : (n - 1);
    int b = blk >> 2;                    // bucket (32*4 = 128 nodes)

    int cr = cnt[cc];
    int m = valid ? (cr < CAP ? cr : CAP) : 0;
    float di = dinv[cc];

    // lane l holds slots 2l, 2l+1: one uint4 = (r0, w0, r1, w1)
    uint4 pe = ((const uint4*)ell2)[(size_t)cc * 8 + l];
    int pr0 = (int)pe.x; float pw0 = __uint_as_float(pe.y);
    int pr1 = (int)pe.z; float pw1 = __uint_as_float(pe.w);

    const uint4* xr4 = (const uint4*)x16;
    uint4 xs = xr4[(size_t)cc * 8 + l];
    float s2 = di * di;                  // self-loop weight = dinv[c]*1*dinv[c]
    float a0 = s2 * bflo(xs.x), a1 = s2 * bfhi(xs.x);
    float a2 = s2 * bflo(xs.y), a3 = s2 * bfhi(xs.y);
    float a4 = s2 * bflo(xs.z), a5 = s2 * bfhi(xs.z);
    float a6 = s2 * bflo(xs.w), a7 = s2 * bfhi(xs.w);

    int base = lane & 56;
    #pragma unroll
    for (int k = 0; k < 8; ++k) {
        int rk = __shfl((k & 1) ? pr1 : pr0, base + (k >> 1));
        float wk = __shfl((k & 1) ? pw1 : pw0, base + (k >> 1));
        bool v = k < m;
        int r = v ? rk : 0;
        float w = v ? wk : 0.0f;
        uint4 xr = xr4[(size_t)r * 8 + l];
        a0 = fmaf(w, bflo(xr.x), a0); a1 = fmaf(w, bfhi(xr.x), a1);
        a2 = fmaf(w, bflo(xr.y), a2); a3 = fmaf(w, bfhi(xr.y), a3);
        a4 = fmaf(w, bflo(xr.z), a4); a5 = fmaf(w, bfhi(xr.z), a5);
        a6 = fmaf(w, bflo(xr.w), a6); a7 = fmaf(w, bfhi(xr.w), a7);
    }
    if (__any(m > 8)) {
        #pragma unroll
        for (int k = 8; k < CAP; ++k) {
            int rk = __shfl((k & 1) ? pr1 : pr0, base + (k >> 1));
            float wk = __shfl((k & 1) ? pw1 : pw0, base + (k >> 1));
            bool v = k < m;
            int r = v ? rk : 0;
            float w = v ? wk : 0.0f;
            uint4 xr = xr4[(size_t)r * 8 + l];
            a0 = fmaf(w, bflo(xr.x), a0); a1 = fmaf(w, bfhi(xr.x), a1);
            a2 = fmaf(w, bflo(xr.y), a2); a3 = fmaf(w, bfhi(xr.y), a3);
            a4 = fmaf(w, bflo(xr.z), a4); a5 = fmaf(w, bfhi(xr.z), a5);
            a6 = fmaf(w, bflo(xr.w), a6); a7 = fmaf(w, bfhi(xr.w), a7);
        }
    }
    // overflow entries for this bucket (deg > CAP; ~1 per bucket avg)
    int novb = ovfc[b];
    for (int i = 0; i < novb; ++i) {
        int2 ent = ovfe[(size_t)b * OVR + i];
        int cl = ent.x & (BND - 1);
        int r = ent.x >> BSH;
        float wm = ((b << BSH) + cl == cc && valid) ? __int_as_float(ent.y) : 0.0f;
        uint4 xr = xr4[(size_t)r * 8 + l];
        a0 = fmaf(wm, bflo(xr.x), a0); a1 = fmaf(wm, bfhi(xr.x), a1);
        a2 = fmaf(wm, bflo(xr.y), a2); a3 = fmaf(wm, bfhi(xr.y), a3);
        a4 = fmaf(wm, bflo(xr.z), a4); a5 = fmaf(wm, bfhi(xr.z), a5);
        a6 = fmaf(wm, bflo(xr.w), a6); a7 = fmaf(wm, bfhi(xr.w), a7);
    }

    if (valid) {
        uint4 ho;
        ho.x = pack2bf(a0, a1); ho.y = pack2bf(a2, a3);
        ho.z = pack2bf(a4, a5); ho.w = pack2bf(a6, a7);
        ((uint4*)agg16)[(size_t)cc * 8 + l] = ho;
    }
    const float4* wp4 = (const float4*)Wp;
    float4 w0 = wp4[2 * l], w1 = wp4[2 * l + 1];
    float part = a0 * w0.x + a1 * w0.y + a2 * w0.z + a3 * w0.w
               + a4 * w1.x + a5 * w1.y + a6 * w1.z + a7 * w1.w;
    part += __shfl_xor(part, 1);
    part += __shfl_xor(part, 2);
    part += __shfl_xor(part, 4);
    if (l == 0 && valid) score[c] = part + bp[0];
}

// POOL_SPLIT blocks per graph. Fused per-graph softmax; W column in 16 NAMED
// float4s; node agg row staged via LDS broadcast; 4 FMA chains; prefetch.
#define WLOAD(i) float4 wq##i = make_float4(We[(4*(i)+0)*NIN+lane], We[(4*(i)+1)*NIN+lane], \
                                            We[(4*(i)+2)*NIN+lane], We[(4*(i)+3)*NIN+lane]);
#define WSTEP(i) { float4 av = *(const float4*)&als[wv][4*(i)]; \
    e0 = fmaf(av.x, wq##i.x, e0); e1 = fmaf(av.y, wq##i.y, e1); \
    e2 = fmaf(av.z, wq##i.z, e2); e3 = fmaf(av.w, wq##i.w, e3); }

__global__ void __launch_bounds__(256)
k_pool(const ushort* __restrict__ agg16, const float* __restrict__ score,
       const float* __restrict__ We, const float* __restrict__ be,
       const int* __restrict__ gstart, const int* __restrict__ gend,
       float* __restrict__ out) {
    int g = blockIdx.x / POOL_SPLIT;
    int p = blockIdx.x % POOL_SPLIT;
    int tid = threadIdx.x;
    int wv = tid >> 6, lane = tid & 63;
    int s = gstart[g], e = gend[g];

    __shared__ float red[4];
    __shared__ float bc;

    float mx = -3.402823466e38f;
    for (int i = s + tid; i < e; i += 256) mx = fmaxf(mx, score[i]);
    #pragma unroll
    for (int off = 32; off > 0; off >>= 1) mx = fmaxf(mx, __shfl_xor(mx, off));
    if (lane == 0) red[wv] = mx;
    __syncthreads();
    if (tid == 0) bc = fmaxf(fmaxf(red[0], red[1]), fmaxf(red[2], red[3]));
    __syncthreads();
    float m = bc;
    __syncthreads();

    float sm = 0.0f;
    for (int i = s + tid; i < e; i += 256) sm += __expf(score[i] - m);
    sm = wave_reduce_sum(sm);
    if (lane == 0) red[wv] = sm;
    __syncthreads();
    if (tid == 0) bc = red[0] + red[1] + red[2] + red[3];
    __syncthreads();
    float invz = (bc > 0.0f) ? 1.0f / bc : 0.0f;

    WLOAD(0) WLOAD(1) WLOAD(2) WLOAD(3) WLOAD(4) WLOAD(5) WLOAD(6) WLOAD(7)
    WLOAD(8) WLOAD(9) WLOAD(10) WLOAD(11) WLOAD(12) WLOAD(13) WLOAD(14) WLOAD(15)
    float bj = be[lane];

    __shared__ float als[4][NIN];
    __shared__ float part[4][NIN];

    const int stride = POOL_SPLIT * 4;
    int n = s + p * 4 + wv;
    float acc = 0.0f;

    float a_cur = 0.0f, sw_cur = 0.0f;
    if (n < e) {
        a_cur = bf2f(agg16[(size_t)n * NIN + lane]);
        sw_cur = __expf(score[n] - m) * invz;
    }
    while (n < e) {
        int nn = n + stride;
        bool vn = nn < e;
        int ni = vn ? nn : n;
        float a_nxt = bf2f(agg16[(size_t)ni * NIN + lane]);   // prefetch
        float sw_nxt = __expf(score[ni] - m) * invz;

        als[wv][lane] = a_cur;
        float e0 = bj, e1 = 0.0f, e2 = 0.0f, e3 = 0.0f;
        WSTEP(0) WSTEP(1) WSTEP(2) WSTEP(3) WSTEP(4) WSTEP(5) WSTEP(6) WSTEP(7)
        WSTEP(8) WSTEP(9) WSTEP(10) WSTEP(11) WSTEP(12) WSTEP(13) WSTEP(14) WSTEP(15)
        float emb = fmaxf(e0 + e1 + e2 + e3, 0.0f);
        acc = fmaf(sw_cur, emb, acc);

        a_cur = a_nxt; sw_cur = sw_nxt;
        n = nn;
    }
    part[wv][lane] = acc;
    __syncthreads();
    if (wv == 0) {
        float r = part[0][lane] + part[1][lane] + part[2][lane] + part[3][lane];
        atomicAdd(&out[(size_t)g * NIN + lane], r);
    }
}

extern "C" void kernel_launch(void* const* d_in, const int* in_sizes, int n_in,
                              void* d_out, int out_size, void* d_ws, size_t ws_size,
                              hipStream_t stream) {
    const float* x  = (const float*)d_in[0];
    const float* We = (const float*)d_in[1];
    const float* be = (const float*)d_in[2];
    const float* Wp = (const float*)d_in[3];
    const float* bp = (const float*)d_in[4];
    const float* ew = (const float*)d_in[5];
    const int* eidx = (const int*)d_in[6];
    const int* seg  = (const int*)d_in[7];

    int N = in_sizes[0] / NIN;
    int E = in_sizes[5];
    const int* row = eidx;
    const int* col = eidx + E;
    int nb   = (N + BND - 1) / BND;       // 782
    int nblk = (E + CHUNK - 1) / CHUNK;   // 782

    char* w = (char*)d_ws;
    auto alloc = [&](size_t bytes) {
        char* p = w;
        w += (bytes + 255) & ~(size_t)255;
        return p;
    };
    unsigned short* x16    = (unsigned short*)alloc((size_t)N * NIN * sizeof(short));
    unsigned short* agg16  = (unsigned short*)alloc((size_t)N * NIN * sizeof(short));
    float*          dinv   = (float*)alloc((size_t)N * sizeof(float));
    int*            cnt    = (int*)  alloc((size_t)N * sizeof(int));
    uint2*          bins   = (uint2*)alloc((size_t)E * sizeof(uint2));
    int2*           ell2   = (int2*) alloc((size_t)N * CAP * sizeof(int2));
    int*            ghist  = (int*)  alloc((size_t)nblk * nb * sizeof(int));
    int*            btot   = (int*)  alloc((size_t)nb * sizeof(int));
    int*            ovfc   = (int*)  alloc((size_t)nb * sizeof(int));
    int2*           ovfe   = (int2*) alloc((size_t)nb * OVR * sizeof(int2));
    float*          score  = (float*)alloc((size_t)N * sizeof(float));
    int*            gstart = (int*)  alloc(GSEG * sizeof(int));
    int*            gend   = (int*)  alloc(GSEG * sizeof(int));
    float* out = (float*)d_out;

    int b = 256;
    int g_prep   = (N * (NIN / 4) + b - 1) / b;   // 6250 >= nblk
    int g_gather = (N + 31) / 32;                 // 3125

    k_prep<<<g_prep, b, 0, stream>>>((ushort4*)x16, (const float4*)x, out, gstart,
                                     gend, col, ghist, N, E, nb, nblk);
    k_scanA<<<nb, b, 0, stream>>>(ghist, btot, seg, gstart, gend, nblk, nb, N);
    k_scatter<<<nblk, b, 0, stream>>>(row, col, ew, ghist, btot, bins, E, nb);
    k_deg2<<<nb, b, 0, stream>>>(bins, btot, dinv, N, nb);
    k_build<<<nb, b, 0, stream>>>(bins, btot, dinv, ell2, cnt, ovfc, ovfe, N, nb);
    k_gather<<<g_gather, b, 0, stream>>>(x16, dinv, cnt, ell2, ovfc, ovfe,
                                         agg16, Wp, bp, score, N);
    k_pool<<<GSEG * POOL_SPLIT, b, 0, stream>>>(agg16, score, We, be, gstart, gend, out);
}

// Round 17
// 84.850 us; speedup vs baseline: 1.1850x; 1.1850x over previous
//
#include <hip/hip_runtime.h>
#include <math.h>

#define NIN 64
#define CAP 16
#define GSEG 250
#define POOL_SPLIT 8
#define BND 256            // nodes per bucket
#define CHUNK 2048         // edges per hist/scatter chunk
#define NBMAX 512          // max buckets / chunks for scans
#define OVR 128            // per-bucket overflow region (global)

__device__ __forceinline__ float wave_reduce_sum(float v) {
    #pragma unroll
    for (int off = 32; off > 0; off >>= 1) v += __shfl_xor(v, off);
    return v;
}

__device__ __forceinline__ unsigned short f2bf(float f) {
    unsigned int u = __float_as_uint(f);
    u += 0x7FFFu + ((u >> 16) & 1u);   // round-to-nearest-even
    return (unsigned short)(u >> 16);
}
__device__ __forceinline__ float bf2f(unsigned short h) {
    return __uint_as_float(((unsigned int)h) << 16);
}
__device__ __forceinline__ float bflo(unsigned int u) { return __uint_as_float(u << 16); }
__device__ __forceinline__ float bfhi(unsigned int u) { return __uint_as_float(u & 0xFFFF0000u); }
__device__ __forceinline__ unsigned int pack2bf(float lo, float hi) {
    return (unsigned int)f2bf(lo) | ((unsigned int)f2bf(hi) << 16);
}

// 15-bit float for w in (0,1]: 5-bit exp, 10-bit mantissa.
__device__ __forceinline__ unsigned int f15enc(float w) {
    unsigned int u = __float_as_uint(w);           // w >= 0
    u += 0x0FFFu + ((u >> 13) & 1u);               // RNE to 10-bit mantissa
    int e5 = (int)(u >> 23) - 96;
    if (e5 <= 0) return 0u;                        // underflow -> 0 (negligible)
    unsigned int m = (u >> 13) & 0x3FFu;
    if (e5 > 31) { e5 = 31; m = 0x3FFu; }
    return ((unsigned int)e5 << 10) | m;
}
__device__ __forceinline__ float f15dec(unsigned int f) {
    if (f == 0u) return 0.0f;
    return __uint_as_float((((f >> 10) + 96u) << 23) | ((f & 0x3FFu) << 13));
}

// exclusive prefix of x across the 64-lane wave
__device__ __forceinline__ int wave_excl_scan_int(int x, int lane) {
    int inc = x;
    #pragma unroll
    for (int off = 1; off < 64; off <<= 1) {
        int y = __shfl_up(inc, off);
        if (lane >= off) inc += y;
    }
    return inc - x;
}

// wave0: exclusive scan of src[0..nb) (nb <= 512) into dst (LDS).
__device__ __forceinline__ void scan_btot(const int* __restrict__ src,
                                          int* dst, int nb, int tid) {
    if (tid < 64) {
        int v[8];
        #pragma unroll
        for (int j = 0; j < 8; ++j) {
            int idx = tid * 8 + j;
            v[j] = (idx < nb) ? src[idx] : 0;
        }
        int loc = 0;
        #pragma unroll
        for (int j = 0; j < 8; ++j) loc += v[j];
        int ex = wave_excl_scan_int(loc, tid);
        int run = ex;
        #pragma unroll
        for (int j = 0; j < 8; ++j) {
            int idx = tid * 8 + j;
            if (idx < nb) { dst[idx] = run; run += v[j]; }
        }
    }
}

// prep: x16 = bf16(x); zero out/bounds; per-chunk LDS histogram.
__global__ void __launch_bounds__(256)
k_prep(ushort4* __restrict__ x164, const float4* __restrict__ x4,
       float* __restrict__ out, int* __restrict__ gstart, int* __restrict__ gend,
       const int* __restrict__ col, int* __restrict__ ghist,
       int n, int e, int nb, int nblk) {
    __shared__ int h[NBMAX];
    int tid = threadIdx.x, blk = blockIdx.x;
    int i = blk * 256 + tid;
    int tot = n * (NIN / 4);
    if (i < tot) {
        float4 v = x4[i];
        ushort4 hh;
        hh.x = f2bf(v.x); hh.y = f2bf(v.y); hh.z = f2bf(v.z); hh.w = f2bf(v.w);
        x164[i] = hh;
    }
    if (i < GSEG * NIN) out[i] = 0.0f;
    if (i < GSEG) { gstart[i] = 0; gend[i] = 0; }
    if (blk < nblk) {
        for (int j = tid; j < NBMAX; j += 256) h[j] = 0;
        __syncthreads();
        int base = blk * CHUNK;
        int end = base + CHUNK; if (end > e) end = e;
        for (int j = base + tid; j < end; j += 256) atomicAdd(&h[col[j] >> 8], 1);
        __syncthreads();
        for (int b = tid; b < nb; b += 256) ghist[blk * nb + b] = h[b];
    }
}

// scanA: per-bucket exclusive scan across chunks; segment bounds grid-stride.
__global__ void k_scanA(int* __restrict__ ghist, int* __restrict__ btot,
                        const int* __restrict__ seg, int* __restrict__ gstart,
                        int* __restrict__ gend, int nblk, int nb, int n) {
    int b = blockIdx.x, lane = threadIdx.x;
    int v[8];
    #pragma unroll
    for (int j = 0; j < 8; ++j) {
        int idx = lane * 8 + j;
        v[j] = (idx < nblk) ? ghist[idx * nb + b] : 0;
    }
    int loc = 0;
    #pragma unroll
    for (int j = 0; j < 8; ++j) loc += v[j];
    int ex = wave_excl_scan_int(loc, lane);
    int run = ex;
    #pragma unroll
    for (int j = 0; j < 8; ++j) {
        int idx = lane * 8 + j;
        if (idx < nblk) { int t = v[j]; ghist[idx * nb + b] = run; run += t; }
    }
    if (lane == 63) btot[b] = ex + loc;

    int gsz = gridDim.x * 64;
    for (int i = b * 64 + lane; i < n; i += gsz) {
        int s = seg[i];
        if (i == 0 || seg[i - 1] != s) gstart[s] = i;
        if (i == n - 1 || seg[i + 1] != s) gend[s] = i + 1;
    }
}

// scatter: records (r, cl|f15(ew)) sorted by bucket in LDS, contiguous copy-out.
__global__ void __launch_bounds__(256)
k_scatter(const int* __restrict__ row, const int* __restrict__ col,
          const float* __restrict__ ew, const int* __restrict__ ghist,
          const int* __restrict__ btot, uint2* __restrict__ bins,
          int e, int nb) {
    __shared__ int h[NBMAX];
    __shared__ int loff[NBMAX];
    __shared__ int gdst[NBMAX];
    __shared__ int bb[NBMAX];
    __shared__ uint2 recs[CHUNK];
    __shared__ unsigned short rb[CHUNK];
    int tid = threadIdx.x, blk = blockIdx.x;
    int base = blk * CHUNK;
    int end = base + CHUNK; if (end > e) end = e;
    int cntc = end - base;

    for (int i = tid; i < NBMAX; i += 256) h[i] = 0;
    __syncthreads();
    for (int i = base + tid; i < end; i += 256) atomicAdd(&h[col[i] >> 8], 1);
    __syncthreads();
    if (tid < 64) {
        int v[8];
        #pragma unroll
        for (int j = 0; j < 8; ++j) {
            int idx = tid * 8 + j;
            v[j] = (idx < nb) ? h[idx] : 0;
        }
        int loc = 0;
        #pragma unroll
        for (int j = 0; j < 8; ++j) loc += v[j];
        int ex = wave_excl_scan_int(loc, tid);
        int run = ex;
        #pragma unroll
        for (int j = 0; j < 8; ++j) {
            int idx = tid * 8 + j;
            if (idx < nb) { loff[idx] = run; run += v[j]; }
        }
    }
    scan_btot(btot, bb, nb, tid);
    __syncthreads();
    for (int b = tid; b < nb; b += 256) gdst[b] = bb[b] + ghist[blk * nb + b];
    for (int i = tid; i < NBMAX; i += 256) h[i] = 0;
    __syncthreads();
    for (int i = base + tid; i < end; i += 256) {
        int c = col[i], r = row[i];
        int b = c >> 8;
        uint2 rec;
        rec.x = (unsigned int)r;
        rec.y = ((unsigned int)(c & (BND - 1)) << 15) | f15enc(ew[i]);
        int k = atomicAdd(&h[b], 1);
        int idx = loff[b] + k;
        recs[idx] = rec;
        rb[idx] = (unsigned short)b;
    }
    __syncthreads();
    for (int i = tid; i < cntc; i += 256) {
        int b = rb[i];
        bins[(size_t)gdst[b] + (i - loff[b])] = recs[i];
    }
}

// build: one block per bucket; contiguous record range; ELL(u32)+deg+cnt in
// LDS, burst-write. Overflow (deg > CAP) -> per-bucket global region, consumed
// inline by gather (no aggf, no k_ovf launch, no global atomics).
__global__ void __launch_bounds__(256)
k_build(const uint2* __restrict__ bins, const int* __restrict__ btot,
        unsigned int* __restrict__ ell, float* __restrict__ deg,
        int* __restrict__ cnt, int* __restrict__ ovfc, int2* __restrict__ ovfe,
        int n, int nb) {
    __shared__ unsigned int tile[BND * CAP];   // 16 KB
    __shared__ float sdeg[BND];
    __shared__ int scnt[BND];
    __shared__ int bb[NBMAX];
    __shared__ int2 sovf[OVR];
    __shared__ int sovn;
    int tid = threadIdx.x;
    int b = blockIdx.x;
    int c0 = b << 8;
    int nn = n - c0; if (nn > BND) nn = BND;
    sdeg[tid] = 0.0f; scnt[tid] = 0;
    if (tid == 0) sovn = 0;
    for (int i = tid; i < BND * CAP; i += 256) tile[i] = 0u;
    scan_btot(btot, bb, nb, tid);
    __syncthreads();
    int s0 = bb[b], tot = btot[b];
    for (int i = tid; i < tot; i += 256) {
        uint2 rec = bins[(size_t)s0 + i];
        int cl = (int)((rec.y >> 15) & (BND - 1));
        unsigned int w15 = rec.y & 0x7FFFu;
        atomicAdd(&sdeg[cl], f15dec(w15));
        int slot = atomicAdd(&scnt[cl], 1);
        unsigned int p = (rec.x << 15) | w15;
        if (slot < CAP) {
            tile[cl * CAP + slot] = p;
        } else {
            int oi = atomicAdd(&sovn, 1);
            if (oi < OVR) sovf[oi] = make_int2(((int)rec.x << 8) | cl, (int)w15);
        }
    }
    __syncthreads();
    for (int i = tid; i < nn * CAP; i += 256)
        ell[(size_t)c0 * CAP + i] = tile[i];
    if (tid < nn) {
        deg[c0 + tid] = sdeg[tid] + 1.0f;   // raw degree incl. self-loop
        cnt[c0 + tid] = scnt[tid];
    }
    int nov = sovn < OVR ? sovn : OVR;
    if (tid == 0) ovfc[b] = nov;
    for (int i = tid; i < nov; i += 256) ovfe[(size_t)b * OVR + i] = sovf[i];
}

// gather: 3125 blocks x 32 nodes (all within one 256-node bucket).
// 8 nodes/wave, 8 lanes/node, uint4 (8 bf16) per lane. Overflow entries for
// this bucket applied inline in the pre-scale section (then x di with rest).
__global__ void __launch_bounds__(256)
k_gather(const ushort* __restrict__ x16, const float* __restrict__ deg,
         const int* __restrict__ cnt, const unsigned int* __restrict__ ell,
         const int* __restrict__ ovfc, const int2* __restrict__ ovfe,
         ushort* __restrict__ agg16, const float* __restrict__ Wp,
         const float* __restrict__ bp, float* __restrict__ score, int n) {
    int tid = threadIdx.x, blk = blockIdx.x;
    int lane = tid & 63, wv = tid >> 6;
    int o = lane >> 3, l = lane & 7;
    int c = blk * 32 + wv * 8 + o;
    bool valid = c < n;
    int cc = valid ? c : (n - 1);
    int b = blk >> 3;                    // bucket (32*8 = 256 nodes)

    int cr = cnt[cc];
    int m = valid ? (cr < CAP ? cr : CAP) : 0;
    float di = rsqrtf(deg[cc]);

    // lane l holds slots 2l, 2l+1 of its node's ELL row
    const uint2* ell2 = (const uint2*)ell;
    uint2 pe = ell2[(size_t)cc * 8 + l];
    int pr0 = (int)(pe.x >> 15);
    float pw0 = f15dec(pe.x & 0x7FFFu) * rsqrtf(deg[pr0]);
    int pr1 = (int)(pe.y >> 15);
    float pw1 = f15dec(pe.y & 0x7FFFu) * rsqrtf(deg[pr1]);

    const uint4* xr4 = (const uint4*)x16;
    uint4 xs = xr4[(size_t)cc * 8 + l];
    float a0 = di * bflo(xs.x), a1 = di * bfhi(xs.x);
    float a2 = di * bflo(xs.y), a3 = di * bfhi(xs.y);
    float a4 = di * bflo(xs.z), a5 = di * bfhi(xs.z);
    float a6 = di * bflo(xs.w), a7 = di * bfhi(xs.w);

    int base = lane & 56;
    #pragma unroll
    for (int k = 0; k < 8; ++k) {
        int rk = __shfl((k & 1) ? pr1 : pr0, base + (k >> 1));
        float wk = __shfl((k & 1) ? pw1 : pw0, base + (k >> 1));
        bool v = k < m;
        int r = v ? rk : 0;
        float w = v ? wk : 0.0f;
        uint4 xr = xr4[(size_t)r * 8 + l];
        a0 = fmaf(w, bflo(xr.x), a0); a1 = fmaf(w, bfhi(xr.x), a1);
        a2 = fmaf(w, bflo(xr.y), a2); a3 = fmaf(w, bfhi(xr.y), a3);
        a4 = fmaf(w, bflo(xr.z), a4); a5 = fmaf(w, bfhi(xr.z), a5);
        a6 = fmaf(w, bflo(xr.w), a6); a7 = fmaf(w, bfhi(xr.w), a7);
    }
    if (__any(m > 8)) {
        #pragma unroll
        for (int k = 8; k < CAP; ++k) {
            int rk = __shfl((k & 1) ? pr1 : pr0, base + (k >> 1));
            float wk = __shfl((k & 1) ? pw1 : pw0, base + (k >> 1));
            bool v = k < m;
            int r = v ? rk : 0;
            float w = v ? wk : 0.0f;
            uint4 xr = xr4[(size_t)r * 8 + l];
            a0 = fmaf(w, bflo(xr.x), a0); a1 = fmaf(w, bfhi(xr.x), a1);
            a2 = fmaf(w, bflo(xr.y), a2); a3 = fmaf(w, bfhi(xr.y), a3);
            a4 = fmaf(w, bflo(xr.z), a4); a5 = fmaf(w, bfhi(xr.z), a5);
            a6 = fmaf(w, bflo(xr.w), a6); a7 = fmaf(w, bfhi(xr.w), a7);
        }
    }
    // overflow entries for this bucket (deg > CAP; ~1-2 nodes per bucket)
    int novb = ovfc[b];
    int nl = cc & (BND - 1);
    for (int i = 0; i < novb; ++i) {
        int2 ent = ovfe[(size_t)b * OVR + i];
        int cl = ent.x & (BND - 1);
        int r = ent.x >> 8;
        bool mine = (cl == nl) && valid;
        float wm = mine ? f15dec((unsigned int)ent.y) * rsqrtf(deg[r]) : 0.0f;
        uint4 xr = xr4[(size_t)r * 8 + l];
        a0 = fmaf(wm, bflo(xr.x), a0); a1 = fmaf(wm, bfhi(xr.x), a1);
        a2 = fmaf(wm, bflo(xr.y), a2); a3 = fmaf(wm, bfhi(xr.y), a3);
        a4 = fmaf(wm, bflo(xr.z), a4); a5 = fmaf(wm, bfhi(xr.z), a5);
        a6 = fmaf(wm, bflo(xr.w), a6); a7 = fmaf(wm, bfhi(xr.w), a7);
    }
    a0 *= di; a1 *= di; a2 *= di; a3 *= di;
    a4 *= di; a5 *= di; a6 *= di; a7 *= di;

    if (valid) {
        uint4 ho;
        ho.x = pack2bf(a0, a1); ho.y = pack2bf(a2, a3);
        ho.z = pack2bf(a4, a5); ho.w = pack2bf(a6, a7);
        ((uint4*)agg16)[(size_t)cc * 8 + l] = ho;
    }
    const float4* wp4 = (const float4*)Wp;
    float4 w0 = wp4[2 * l], w1 = wp4[2 * l + 1];
    float part = a0 * w0.x + a1 * w0.y + a2 * w0.z + a3 * w0.w
               + a4 * w1.x + a5 * w1.y + a6 * w1.z + a7 * w1.w;
    part += __shfl_xor(part, 1);
    part += __shfl_xor(part, 2);
    part += __shfl_xor(part, 4);
    if (l == 0 && valid) score[c] = part + bp[0];
}

// POOL_SPLIT blocks per graph. Fused per-graph softmax; W column in 16 NAMED
// float4s; node agg row staged via LDS broadcast; 4 FMA chains; prefetch.
#define WLOAD(i) float4 wq##i = make_float4(We[(4*(i)+0)*NIN+lane], We[(4*(i)+1)*NIN+lane], \
                                            We[(4*(i)+2)*NIN+lane], We[(4*(i)+3)*NIN+lane]);
#define WSTEP(i) { float4 av = *(const float4*)&als[wv][4*(i)]; \
    e0 = fmaf(av.x, wq##i.x, e0); e1 = fmaf(av.y, wq##i.y, e1); \
    e2 = fmaf(av.z, wq##i.z, e2); e3 = fmaf(av.w, wq##i.w, e3); }

__global__ void __launch_bounds__(256)
k_pool(const ushort* __restrict__ agg16, const float* __restrict__ score,
       const float* __restrict__ We, const float* __restrict__ be,
       const int* __restrict__ gstart, const int* __restrict__ gend,
       float* __restrict__ out) {
    int g = blockIdx.x / POOL_SPLIT;
    int p = blockIdx.x % POOL_SPLIT;
    int tid = threadIdx.x;
    int wv = tid >> 6, lane = tid & 63;
    int s = gstart[g], e = gend[g];

    __shared__ float red[4];
    __shared__ float bc;

    float mx = -3.402823466e38f;
    for (int i = s + tid; i < e; i += 256) mx = fmaxf(mx, score[i]);
    #pragma unroll
    for (int off = 32; off > 0; off >>= 1) mx = fmaxf(mx, __shfl_xor(mx, off));
    if (lane == 0) red[wv] = mx;
    __syncthreads();
    if (tid == 0) bc = fmaxf(fmaxf(red[0], red[1]), fmaxf(red[2], red[3]));
    __syncthreads();
    float m = bc;
    __syncthreads();

    float sm = 0.0f;
    for (int i = s + tid; i < e; i += 256) sm += __expf(score[i] - m);
    sm = wave_reduce_sum(sm);
    if (lane == 0) red[wv] = sm;
    __syncthreads();
    if (tid == 0) bc = red[0] + red[1] + red[2] + red[3];
    __syncthreads();
    float invz = (bc > 0.0f) ? 1.0f / bc : 0.0f;

    WLOAD(0) WLOAD(1) WLOAD(2) WLOAD(3) WLOAD(4) WLOAD(5) WLOAD(6) WLOAD(7)
    WLOAD(8) WLOAD(9) WLOAD(10) WLOAD(11) WLOAD(12) WLOAD(13) WLOAD(14) WLOAD(15)
    float bj = be[lane];

    __shared__ float als[4][NIN];
    __shared__ float part[4][NIN];

    const int stride = POOL_SPLIT * 4;
    int n = s + p * 4 + wv;
    float acc = 0.0f;

    float a_cur = 0.0f, sw_cur = 0.0f;
    if (n < e) {
        a_cur = bf2f(agg16[(size_t)n * NIN + lane]);
        sw_cur = __expf(score[n] - m) * invz;
    }
    while (n < e) {
        int nn = n + stride;
        bool vn = nn < e;
        int ni = vn ? nn : n;
        float a_nxt = bf2f(agg16[(size_t)ni * NIN + lane]);   // prefetch
        float sw_nxt = __expf(score[ni] - m) * invz;

        als[wv][lane] = a_cur;
        float e0 = bj, e1 = 0.0f, e2 = 0.0f, e3 = 0.0f;
        WSTEP(0) WSTEP(1) WSTEP(2) WSTEP(3) WSTEP(4) WSTEP(5) WSTEP(6) WSTEP(7)
        WSTEP(8) WSTEP(9) WSTEP(10) WSTEP(11) WSTEP(12) WSTEP(13) WSTEP(14) WSTEP(15)
        float emb = fmaxf(e0 + e1 + e2 + e3, 0.0f);
        acc = fmaf(sw_cur, emb, acc);

        a_cur = a_nxt; sw_cur = sw_nxt;
        n = nn;
    }
    part[wv][lane] = acc;
    __syncthreads();
    if (wv == 0) {
        float r = part[0][lane] + part[1][lane] + part[2][lane] + part[3][lane];
        atomicAdd(&out[(size_t)g * NIN + lane], r);
    }
}

extern "C" void kernel_launch(void* const* d_in, const int* in_sizes, int n_in,
                              void* d_out, int out_size, void* d_ws, size_t ws_size,
                              hipStream_t stream) {
    const float* x  = (const float*)d_in[0];
    const float* We = (const float*)d_in[1];
    const float* be = (const float*)d_in[2];
    const float* Wp = (const float*)d_in[3];
    const float* bp = (const float*)d_in[4];
    const float* ew = (const float*)d_in[5];
    const int* eidx = (const int*)d_in[6];
    const int* seg  = (const int*)d_in[7];

    int N = in_sizes[0] / NIN;
    int E = in_sizes[5];
    const int* row = eidx;
    const int* col = eidx + E;
    int nb   = (N + BND - 1) / BND;       // 391
    int nblk = (E + CHUNK - 1) / CHUNK;   // 391

    char* w = (char*)d_ws;
    auto alloc = [&](size_t bytes) {
        char* p = w;
        w += (bytes + 255) & ~(size_t)255;
        return p;
    };
    unsigned short* x16    = (unsigned short*)alloc((size_t)N * NIN * sizeof(short));
    unsigned short* agg16  = (unsigned short*)alloc((size_t)N * NIN * sizeof(short));
    float*          deg    = (float*)alloc((size_t)N * sizeof(float));
    int*            cnt    = (int*)  alloc((size_t)N * sizeof(int));
    unsigned int*   ell    = (unsigned int*)alloc((size_t)N * CAP * sizeof(unsigned int));
    uint2*          bins   = (uint2*)alloc((size_t)E * sizeof(uint2));
    int*            ghist  = (int*)  alloc((size_t)nblk * nb * sizeof(int));
    int*            btot   = (int*)  alloc((size_t)nb * sizeof(int));
    int*            ovfc   = (int*)  alloc((size_t)nb * sizeof(int));
    int2*           ovfe   = (int2*) alloc((size_t)nb * OVR * sizeof(int2));
    float*          score  = (float*)alloc((size_t)N * sizeof(float));
    int*            gstart = (int*)  alloc(GSEG * sizeof(int));
    int*            gend   = (int*)  alloc(GSEG * sizeof(int));
    float* out = (float*)d_out;

    int b = 256;
    int g_prep   = (N * (NIN / 4) + b - 1) / b;   // 6250 >= nblk
    int g_gather = (N + 31) / 32;                 // 3125

    k_prep<<<g_prep, b, 0, stream>>>((ushort4*)x16, (const float4*)x, out, gstart,
                                     gend, col, ghist, N, E, nb, nblk);
    k_scanA<<<nb, 64, 0, stream>>>(ghist, btot, seg, gstart, gend, nblk, nb, N);
    k_scatter<<<nblk, b, 0, stream>>>(row, col, ew, ghist, btot, bins, E, nb);
    k_build<<<nb, b, 0, stream>>>(bins, btot, ell, deg, cnt, ovfc, ovfe, N, nb);
    k_gather<<<g_gather, b, 0, stream>>>(x16, deg, cnt, ell, ovfc, ovfe,
                                         agg16, Wp, bp, score, N);
    k_pool<<<GSEG * POOL_SPLIT, b, 0, stream>>>(agg16, score, We, be, gstart, gend, out);
}

// Round 18
// 83.715 us; speedup vs baseline: 1.2011x; 1.0136x over previous
//
#include <hip/hip_runtime.h>
#include <math.h>

#define NIN 64
#define CAP 16
#define GSEG 250
#define POOL_SPLIT 4
#define BND 256            // nodes per bucket
#define CHUNK 2048         // edges per hist/scatter chunk
#define NBMAX 512          // max buckets / chunks for scans
#define OVR 128            // per-bucket overflow region (global)

__device__ __forceinline__ float wave_reduce_sum(float v) {
    #pragma unroll
    for (int off = 32; off > 0; off >>= 1) v += __shfl_xor(v, off);
    return v;
}

__device__ __forceinline__ unsigned short f2bf(float f) {
    unsigned int u = __float_as_uint(f);
    u += 0x7FFFu + ((u >> 16) & 1u);   // round-to-nearest-even
    return (unsigned short)(u >> 16);
}
__device__ __forceinline__ float bf2f(unsigned short h) {
    return __uint_as_float(((unsigned int)h) << 16);
}
__device__ __forceinline__ float bflo(unsigned int u) { return __uint_as_float(u << 16); }
__device__ __forceinline__ float bfhi(unsigned int u) { return __uint_as_float(u & 0xFFFF0000u); }
__device__ __forceinline__ unsigned int pack2bf(float lo, float hi) {
    return (unsigned int)f2bf(lo) | ((unsigned int)f2bf(hi) << 16);
}

// 15-bit float for w in (0,1]: 5-bit exp, 10-bit mantissa.
__device__ __forceinline__ unsigned int f15enc(float w) {
    unsigned int u = __float_as_uint(w);           // w >= 0
    u += 0x0FFFu + ((u >> 13) & 1u);               // RNE to 10-bit mantissa
    int e5 = (int)(u >> 23) - 96;
    if (e5 <= 0) return 0u;                        // underflow -> 0 (negligible)
    unsigned int m = (u >> 13) & 0x3FFu;
    if (e5 > 31) { e5 = 31; m = 0x3FFu; }
    return ((unsigned int)e5 << 10) | m;
}
__device__ __forceinline__ float f15dec(unsigned int f) {
    if (f == 0u) return 0.0f;
    return __uint_as_float((((f >> 10) + 96u) << 23) | ((f & 0x3FFu) << 13));
}

// exclusive prefix of x across the 64-lane wave
__device__ __forceinline__ int wave_excl_scan_int(int x, int lane) {
    int inc = x;
    #pragma unroll
    for (int off = 1; off < 64; off <<= 1) {
        int y = __shfl_up(inc, off);
        if (lane >= off) inc += y;
    }
    return inc - x;
}

// wave0: exclusive scan of src[0..nb) (nb <= 512) into dst (LDS).
__device__ __forceinline__ void scan_btot(const int* __restrict__ src,
                                          int* dst, int nb, int tid) {
    if (tid < 64) {
        int v[8];
        #pragma unroll
        for (int j = 0; j < 8; ++j) {
            int idx = tid * 8 + j;
            v[j] = (idx < nb) ? src[idx] : 0;
        }
        int loc = 0;
        #pragma unroll
        for (int j = 0; j < 8; ++j) loc += v[j];
        int ex = wave_excl_scan_int(loc, tid);
        int run = ex;
        #pragma unroll
        for (int j = 0; j < 8; ++j) {
            int idx = tid * 8 + j;
            if (idx < nb) { dst[idx] = run; run += v[j]; }
        }
    }
}

// prep: x16 = bf16(x); zero out/bounds; per-chunk LDS histogram.
__global__ void __launch_bounds__(256)
k_prep(ushort4* __restrict__ x164, const float4* __restrict__ x4,
       float* __restrict__ out, int* __restrict__ gstart, int* __restrict__ gend,
       const int* __restrict__ col, int* __restrict__ ghist,
       int n, int e, int nb, int nblk) {
    __shared__ int h[NBMAX];
    int tid = threadIdx.x, blk = blockIdx.x;
    int i = blk * 256 + tid;
    int tot = n * (NIN / 4);
    if (i < tot) {
        float4 v = x4[i];
        ushort4 hh;
        hh.x = f2bf(v.x); hh.y = f2bf(v.y); hh.z = f2bf(v.z); hh.w = f2bf(v.w);
        x164[i] = hh;
    }
    if (i < GSEG * NIN) out[i] = 0.0f;
    if (i < GSEG) { gstart[i] = 0; gend[i] = 0; }
    if (blk < nblk) {
        for (int j = tid; j < NBMAX; j += 256) h[j] = 0;
        __syncthreads();
        int base = blk * CHUNK;
        int end = base + CHUNK; if (end > e) end = e;
        for (int j = base + tid; j < end; j += 256) atomicAdd(&h[col[j] >> 8], 1);
        __syncthreads();
        for (int b = tid; b < nb; b += 256) ghist[blk * nb + b] = h[b];
    }
}

// scanA: per-bucket exclusive scan across chunks; segment bounds grid-stride.
__global__ void k_scanA(int* __restrict__ ghist, int* __restrict__ btot,
                        const int* __restrict__ seg, int* __restrict__ gstart,
                        int* __restrict__ gend, int nblk, int nb, int n) {
    int b = blockIdx.x, lane = threadIdx.x;
    int v[8];
    #pragma unroll
    for (int j = 0; j < 8; ++j) {
        int idx = lane * 8 + j;
        v[j] = (idx < nblk) ? ghist[idx * nb + b] : 0;
    }
    int loc = 0;
    #pragma unroll
    for (int j = 0; j < 8; ++j) loc += v[j];
    int ex = wave_excl_scan_int(loc, lane);
    int run = ex;
    #pragma unroll
    for (int j = 0; j < 8; ++j) {
        int idx = lane * 8 + j;
        if (idx < nblk) { int t = v[j]; ghist[idx * nb + b] = run; run += t; }
    }
    if (lane == 63) btot[b] = ex + loc;

    int gsz = gridDim.x * 64;
    for (int i = b * 64 + lane; i < n; i += gsz) {
        int s = seg[i];
        if (i == 0 || seg[i - 1] != s) gstart[s] = i;
        if (i == n - 1 || seg[i + 1] != s) gend[s] = i + 1;
    }
}

// scatter: records (r, cl|f15(ew)) sorted by bucket in LDS, contiguous copy-out.
__global__ void __launch_bounds__(256)
k_scatter(const int* __restrict__ row, const int* __restrict__ col,
          const float* __restrict__ ew, const int* __restrict__ ghist,
          const int* __restrict__ btot, uint2* __restrict__ bins,
          int e, int nb) {
    __shared__ int h[NBMAX];
    __shared__ int loff[NBMAX];
    __shared__ int gdst[NBMAX];
    __shared__ int bb[NBMAX];
    __shared__ uint2 recs[CHUNK];
    __shared__ unsigned short rb[CHUNK];
    int tid = threadIdx.x, blk = blockIdx.x;
    int base = blk * CHUNK;
    int end = base + CHUNK; if (end > e) end = e;
    int cntc = end - base;

    for (int i = tid; i < NBMAX; i += 256) h[i] = 0;
    __syncthreads();
    for (int i = base + tid; i < end; i += 256) atomicAdd(&h[col[i] >> 8], 1);
    __syncthreads();
    if (tid < 64) {
        int v[8];
        #pragma unroll
        for (int j = 0; j < 8; ++j) {
            int idx = tid * 8 + j;
            v[j] = (idx < nb) ? h[idx] : 0;
        }
        int loc = 0;
        #pragma unroll
        for (int j = 0; j < 8; ++j) loc += v[j];
        int ex = wave_excl_scan_int(loc, tid);
        int run = ex;
        #pragma unroll
        for (int j = 0; j < 8; ++j) {
            int idx = tid * 8 + j;
            if (idx < nb) { loff[idx] = run; run += v[j]; }
        }
    }
    scan_btot(btot, bb, nb, tid);
    __syncthreads();
    for (int b = tid; b < nb; b += 256) gdst[b] = bb[b] + ghist[blk * nb + b];
    for (int i = tid; i < NBMAX; i += 256) h[i] = 0;
    __syncthreads();
    for (int i = base + tid; i < end; i += 256) {
        int c = col[i], r = row[i];
        int b = c >> 8;
        uint2 rec;
        rec.x = (unsigned int)r;
        rec.y = ((unsigned int)(c & (BND - 1)) << 15) | f15enc(ew[i]);
        int k = atomicAdd(&h[b], 1);
        int idx = loff[b] + k;
        recs[idx] = rec;
        rb[idx] = (unsigned short)b;
    }
    __syncthreads();
    for (int i = tid; i < cntc; i += 256) {
        int b = rb[i];
        bins[(size_t)gdst[b] + (i - loff[b])] = recs[i];
    }
}

// build: one block per bucket; contiguous record range; ELL(u32)+dinv+cnt in
// LDS, burst-write. Emits dinv = rsqrt(deg+1) directly (gather loads it raw).
// Overflow (deg > CAP) -> per-bucket global region, consumed inline by gather.
__global__ void __launch_bounds__(256)
k_build(const uint2* __restrict__ bins, const int* __restrict__ btot,
        unsigned int* __restrict__ ell, float* __restrict__ dinv,
        int* __restrict__ cnt, int* __restrict__ ovfc, int2* __restrict__ ovfe,
        int n, int nb) {
    __shared__ unsigned int tile[BND * CAP];   // 16 KB
    __shared__ float sdeg[BND];
    __shared__ int scnt[BND];
    __shared__ int bb[NBMAX];
    __shared__ int2 sovf[OVR];
    __shared__ int sovn;
    int tid = threadIdx.x;
    int b = blockIdx.x;
    int c0 = b << 8;
    int nn = n - c0; if (nn > BND) nn = BND;
    sdeg[tid] = 0.0f; scnt[tid] = 0;
    if (tid == 0) sovn = 0;
    for (int i = tid; i < BND * CAP; i += 256) tile[i] = 0u;
    scan_btot(btot, bb, nb, tid);
    __syncthreads();
    int s0 = bb[b], tot = btot[b];
    for (int i = tid; i < tot; i += 256) {
        uint2 rec = bins[(size_t)s0 + i];
        int cl = (int)((rec.y >> 15) & (BND - 1));
        unsigned int w15 = rec.y & 0x7FFFu;
        atomicAdd(&sdeg[cl], f15dec(w15));
        int slot = atomicAdd(&scnt[cl], 1);
        unsigned int p = (rec.x << 15) | w15;
        if (slot < CAP) {
            tile[cl * CAP + slot] = p;
        } else {
            int oi = atomicAdd(&sovn, 1);
            if (oi < OVR) sovf[oi] = make_int2(((int)rec.x << 8) | cl, (int)w15);
        }
    }
    __syncthreads();
    for (int i = tid; i < nn * CAP; i += 256)
        ell[(size_t)c0 * CAP + i] = tile[i];
    if (tid < nn) {
        dinv[c0 + tid] = rsqrtf(sdeg[tid] + 1.0f);   // dinv, rsqrt done here
        cnt[c0 + tid] = scnt[tid];
    }
    int nov = sovn < OVR ? sovn : OVR;
    if (tid == 0) ovfc[b] = nov;
    for (int i = tid; i < nov; i += 256) ovfe[(size_t)b * OVR + i] = sovf[i];
}

// gather: 3125 blocks x 32 nodes (all within one 256-node bucket).
// 8 nodes/wave, 8 lanes/node, uint4 (8 bf16) per lane. dinv pre-rsqrt'd.
__global__ void __launch_bounds__(256)
k_gather(const ushort* __restrict__ x16, const float* __restrict__ dinv,
         const int* __restrict__ cnt, const unsigned int* __restrict__ ell,
         const int* __restrict__ ovfc, const int2* __restrict__ ovfe,
         ushort* __restrict__ agg16, const float* __restrict__ Wp,
         const float* __restrict__ bp, float* __restrict__ score, int n) {
    int tid = threadIdx.x, blk = blockIdx.x;
    int lane = tid & 63, wv = tid >> 6;
    int o = lane >> 3, l = lane & 7;
    int c = blk * 32 + wv * 8 + o;
    bool valid = c < n;
    int cc = valid ? c : (n - 1);
    int b = blk >> 3;                    // bucket (32*8 = 256 nodes)

    int cr = cnt[cc];
    int m = valid ? (cr < CAP ? cr : CAP) : 0;
    float di = dinv[cc];

    // lane l holds slots 2l, 2l+1 of its node's ELL row
    const uint2* ell2 = (const uint2*)ell;
    uint2 pe = ell2[(size_t)cc * 8 + l];
    int pr0 = (int)(pe.x >> 15);
    float pw0 = f15dec(pe.x & 0x7FFFu) * dinv[pr0];
    int pr1 = (int)(pe.y >> 15);
    float pw1 = f15dec(pe.y & 0x7FFFu) * dinv[pr1];

    const uint4* xr4 = (const uint4*)x16;
    uint4 xs = xr4[(size_t)cc * 8 + l];
    float a0 = di * bflo(xs.x), a1 = di * bfhi(xs.x);
    float a2 = di * bflo(xs.y), a3 = di * bfhi(xs.y);
    float a4 = di * bflo(xs.z), a5 = di * bfhi(xs.z);
    float a6 = di * bflo(xs.w), a7 = di * bfhi(xs.w);

    int base = lane & 56;
    #pragma unroll
    for (int k = 0; k < 8; ++k) {
        int rk = __shfl((k & 1) ? pr1 : pr0, base + (k >> 1));
        float wk = __shfl((k & 1) ? pw1 : pw0, base + (k >> 1));
        bool v = k < m;
        int r = v ? rk : 0;
        float w = v ? wk : 0.0f;
        uint4 xr = xr4[(size_t)r * 8 + l];
        a0 = fmaf(w, bflo(xr.x), a0); a1 = fmaf(w, bfhi(xr.x), a1);
        a2 = fmaf(w, bflo(xr.y), a2); a3 = fmaf(w, bfhi(xr.y), a3);
        a4 = fmaf(w, bflo(xr.z), a4); a5 = fmaf(w, bfhi(xr.z), a5);
        a6 = fmaf(w, bflo(xr.w), a6); a7 = fmaf(w, bfhi(xr.w), a7);
    }
    if (__any(m > 8)) {
        #pragma unroll
        for (int k = 8; k < CAP; ++k) {
            int rk = __shfl((k & 1) ? pr1 : pr0, base + (k >> 1));
            float wk = __shfl((k & 1) ? pw1 : pw0, base + (k >> 1));
            bool v = k < m;
            int r = v ? rk : 0;
            float w = v ? wk : 0.0f;
            uint4 xr = xr4[(size_t)r * 8 + l];
            a0 = fmaf(w, bflo(xr.x), a0); a1 = fmaf(w, bfhi(xr.x), a1);
            a2 = fmaf(w, bflo(xr.y), a2); a3 = fmaf(w, bfhi(xr.y), a3);
            a4 = fmaf(w, bflo(xr.z), a4); a5 = fmaf(w, bfhi(xr.z), a5);
            a6 = fmaf(w, bflo(xr.w), a6); a7 = fmaf(w, bfhi(xr.w), a7);
        }
    }
    // overflow entries for this bucket (deg > CAP; ~1-2 nodes per bucket)
    int novb = ovfc[b];
    int nl = cc & (BND - 1);
    for (int i = 0; i < novb; ++i) {
        int2 ent = ovfe[(size_t)b * OVR + i];
        int cl = ent.x & (BND - 1);
        int r = ent.x >> 8;
        bool mine = (cl == nl) && valid;
        float wm = mine ? f15dec((unsigned int)ent.y) * dinv[r] : 0.0f;
        uint4 xr = xr4[(size_t)r * 8 + l];
        a0 = fmaf(wm, bflo(xr.x), a0); a1 = fmaf(wm, bfhi(xr.x), a1);
        a2 = fmaf(wm, bflo(xr.y), a2); a3 = fmaf(wm, bfhi(xr.y), a3);
        a4 = fmaf(wm, bflo(xr.z), a4); a5 = fmaf(wm, bfhi(xr.z), a5);
        a6 = fmaf(wm, bflo(xr.w), a6); a7 = fmaf(wm, bfhi(xr.w), a7);
    }
    a0 *= di; a1 *= di; a2 *= di; a3 *= di;
    a4 *= di; a5 *= di; a6 *= di; a7 *= di;

    if (valid) {
        uint4 ho;
        ho.x = pack2bf(a0, a1); ho.y = pack2bf(a2, a3);
        ho.z = pack2bf(a4, a5); ho.w = pack2bf(a6, a7);
        ((uint4*)agg16)[(size_t)cc * 8 + l] = ho;
    }
    const float4* wp4 = (const float4*)Wp;
    float4 w0 = wp4[2 * l], w1 = wp4[2 * l + 1];
    float part = a0 * w0.x + a1 * w0.y + a2 * w0.z + a3 * w0.w
               + a4 * w1.x + a5 * w1.y + a6 * w1.z + a7 * w1.w;
    part += __shfl_xor(part, 1);
    part += __shfl_xor(part, 2);
    part += __shfl_xor(part, 4);
    if (l == 0 && valid) score[c] = part + bp[0];
}

// POOL_SPLIT blocks per graph. Fused per-graph softmax; W column in 16 NAMED
// float4s; node agg row staged via LDS broadcast; 4 FMA chains; prefetch.
#define WLOAD(i) float4 wq##i = make_float4(We[(4*(i)+0)*NIN+lane], We[(4*(i)+1)*NIN+lane], \
                                            We[(4*(i)+2)*NIN+lane], We[(4*(i)+3)*NIN+lane]);
#define WSTEP(i) { float4 av = *(const float4*)&als[wv][4*(i)]; \
    e0 = fmaf(av.x, wq##i.x, e0); e1 = fmaf(av.y, wq##i.y, e1); \
    e2 = fmaf(av.z, wq##i.z, e2); e3 = fmaf(av.w, wq##i.w, e3); }

__global__ void __launch_bounds__(256)
k_pool(const ushort* __restrict__ agg16, const float* __restrict__ score,
       const float* __restrict__ We, const float* __restrict__ be,
       const int* __restrict__ gstart, const int* __restrict__ gend,
       float* __restrict__ out) {
    int g = blockIdx.x / POOL_SPLIT;
    int p = blockIdx.x % POOL_SPLIT;
    int tid = threadIdx.x;
    int wv = tid >> 6, lane = tid & 63;
    int s = gstart[g], e = gend[g];

    __shared__ float red[4];
    __shared__ float bc;

    float mx = -3.402823466e38f;
    for (int i = s + tid; i < e; i += 256) mx = fmaxf(mx, score[i]);
    #pragma unroll
    for (int off = 32; off > 0; off >>= 1) mx = fmaxf(mx, __shfl_xor(mx, off));
    if (lane == 0) red[wv] = mx;
    __syncthreads();
    if (tid == 0) bc = fmaxf(fmaxf(red[0], red[1]), fmaxf(red[2], red[3]));
    __syncthreads();
    float m = bc;
    __syncthreads();

    float sm = 0.0f;
    for (int i = s + tid; i < e; i += 256) sm += __expf(score[i] - m);
    sm = wave_reduce_sum(sm);
    if (lane == 0) red[wv] = sm;
    __syncthreads();
    if (tid == 0) bc = red[0] + red[1] + red[2] + red[3];
    __syncthreads();
    float invz = (bc > 0.0f) ? 1.0f / bc : 0.0f;

    WLOAD(0) WLOAD(1) WLOAD(2) WLOAD(3) WLOAD(4) WLOAD(5) WLOAD(6) WLOAD(7)
    WLOAD(8) WLOAD(9) WLOAD(10) WLOAD(11) WLOAD(12) WLOAD(13) WLOAD(14) WLOAD(15)
    float bj = be[lane];

    __shared__ float als[4][NIN];
    __shared__ float part[4][NIN];

    const int stride = POOL_SPLIT * 4;
    int n = s + p * 4 + wv;
    float acc = 0.0f;

    float a_cur = 0.0f, sw_cur = 0.0f;
    if (n < e) {
        a_cur = bf2f(agg16[(size_t)n * NIN + lane]);
        sw_cur = __expf(score[n] - m) * invz;
    }
    while (n < e) {
        int nn = n + stride;
        bool vn = nn < e;
        int ni = vn ? nn : n;
        float a_nxt = bf2f(agg16[(size_t)ni * NIN + lane]);   // prefetch
        float sw_nxt = __expf(score[ni] - m) * invz;

        als[wv][lane] = a_cur;
        float e0 = bj, e1 = 0.0f, e2 = 0.0f, e3 = 0.0f;
        WSTEP(0) WSTEP(1) WSTEP(2) WSTEP(3) WSTEP(4) WSTEP(5) WSTEP(6) WSTEP(7)
        WSTEP(8) WSTEP(9) WSTEP(10) WSTEP(11) WSTEP(12) WSTEP(13) WSTEP(14) WSTEP(15)
        float emb = fmaxf(e0 + e1 + e2 + e3, 0.0f);
        acc = fmaf(sw_cur, emb, acc);

        a_cur = a_nxt; sw_cur = sw_nxt;
        n = nn;
    }
    part[wv][lane] = acc;
    __syncthreads();
    if (wv == 0) {
        float r = part[0][lane] + part[1][lane] + part[2][lane] + part[3][lane];
        atomicAdd(&out[(size_t)g * NIN + lane], r);
    }
}

extern "C" void kernel_launch(void* const* d_in, const int* in_sizes, int n_in,
                              void* d_out, int out_size, void* d_ws, size_t ws_size,
                              hipStream_t stream) {
    const float* x  = (const float*)d_in[0];
    const float* We = (const float*)d_in[1];
    const float* be = (const float*)d_in[2];
    const float* Wp = (const float*)d_in[3];
    const float* bp = (const float*)d_in[4];
    const float* ew = (const float*)d_in[5];
    const int* eidx = (const int*)d_in[6];
    const int* seg  = (const int*)d_in[7];

    int N = in_sizes[0] / NIN;
    int E = in_sizes[5];
    const int* row = eidx;
    const int* col = eidx + E;
    int nb   = (N + BND - 1) / BND;       // 391
    int nblk = (E + CHUNK - 1) / CHUNK;   // 391

    char* w = (char*)d_ws;
    auto alloc = [&](size_t bytes) {
        char* p = w;
        w += (bytes + 255) & ~(size_t)255;
        return p;
    };
    unsigned short* x16    = (unsigned short*)alloc((size_t)N * NIN * sizeof(short));
    unsigned short* agg16  = (unsigned short*)alloc((size_t)N * NIN * sizeof(short));
    float*          dinv   = (float*)alloc((size_t)N * sizeof(float));
    int*            cnt    = (int*)  alloc((size_t)N * sizeof(int));
    unsigned int*   ell    = (unsigned int*)alloc((size_t)N * CAP * sizeof(unsigned int));
    uint2*          bins   = (uint2*)alloc((size_t)E * sizeof(uint2));
    int*            ghist  = (int*)  alloc((size_t)nblk * nb * sizeof(int));
    int*            btot   = (int*)  alloc((size_t)nb * sizeof(int));
    int*            ovfc   = (int*)  alloc((size_t)nb * sizeof(int));
    int2*           ovfe   = (int2*) alloc((size_t)nb * OVR * sizeof(int2));
    float*          score  = (float*)alloc((size_t)N * sizeof(float));
    int*            gstart = (int*)  alloc(GSEG * sizeof(int));
    int*            gend   = (int*)  alloc(GSEG * sizeof(int));
    float* out = (float*)d_out;

    int b = 256;
    int g_prep   = (N * (NIN / 4) + b - 1) / b;   // 6250 >= nblk
    int g_gather = (N + 31) / 32;                 // 3125

    k_prep<<<g_prep, b, 0, stream>>>((ushort4*)x16, (const float4*)x, out, gstart,
                                     gend, col, ghist, N, E, nb, nblk);
    k_scanA<<<nb, 64, 0, stream>>>(ghist, btot, seg, gstart, gend, nblk, nb, N);
    k_scatter<<<nblk, b, 0, stream>>>(row, col, ew, ghist, btot, bins, E, nb);
    k_build<<<nb, b, 0, stream>>>(bins, btot, ell, dinv, cnt, ovfc, ovfe, N, nb);
    k_gather<<<g_gather, b, 0, stream>>>(x16, dinv, cnt, ell, ovfc, ovfe,
                                         agg16, Wp, bp, score, N);
    k_pool<<<GSEG * POOL_SPLIT, b, 0, stream>>>(agg16, score, We, be, gstart, gend, out);
}